// Round 1
// baseline (403.256 us; speedup 1.0000x reference)
//
#include <hip/hip_runtime.h>

// Masked MSE: out = sum((in-tgt)^2 * (mask==1)) / sum(mask==1)
// Memory-bound 3-stream read reduction (302 MB, no reuse).
// Floor: 302 MB / 6.29 TB/s (measured read ceiling) = 48.0 us.
//
// R6 (prev session): two-stage, zero same-address atomics -> 248.5/245.6 us.
// rocprof shows our kernels < 58.5 us (below the harness's 60 us ws-poison
// fills); headline dur is dominated by fixed per-iteration harness work.
// R7 (this round): fuse stage2 into stage1 via last-block-done finisher.
//   - partials as agent-scope float2{sum,cnt} stores (cnt exact in fp32:
//     per-block cnt <= 8192, total <= 12.6M < 2^24)
//   - ticket traffic split across 8 cache lines (384 adds/line) + 1 global
//     line (8 adds) to avoid re-creating R5's ~14 ns/atomic same-line drain
//   - tickets zeroed by a 64 B hipMemsetAsync node (graph-capturable),
//     replacing the ~5 us stage2 kernel dispatch.

#define BLOCK 256
#define UNROLL 8
#define MAX_PARTS 8192          // float2 partial slots in d_ws (64 KB used)

typedef float vfloat4 __attribute__((ext_vector_type(4)));
typedef float vfloat2 __attribute__((ext_vector_type(2)));
typedef int   vint4   __attribute__((ext_vector_type(4)));

// Agent-scope (device-coherent) 8-byte partial store/load: bypasses the
// non-coherent per-XCD L2 path so the finisher block (any XCD) sees them.
__device__ __forceinline__ void store_part_agent(vfloat2* p, float s, float c)
{
    vfloat2 v; v.x = s; v.y = c;
    unsigned long long u = __builtin_bit_cast(unsigned long long, v);
    __hip_atomic_store((unsigned long long*)p, u, __ATOMIC_RELAXED,
                       __HIP_MEMORY_SCOPE_AGENT);
}
__device__ __forceinline__ vfloat2 load_part_agent(const vfloat2* p)
{
    unsigned long long u = __hip_atomic_load((const unsigned long long*)p,
                                             __ATOMIC_RELAXED,
                                             __HIP_MEMORY_SCOPE_AGENT);
    return __builtin_bit_cast(vfloat2, u);
}

// FINISH=1: last block reduces all partials and writes out (no stage2).
// FINISH=0: partial-only (fallback path when a tail kernel is needed).
template <int FINISH>
__global__ __launch_bounds__(BLOCK, 2) void masked_mse_fused(
    const vfloat4* __restrict__ inp,
    const vfloat4* __restrict__ tgt,
    const vint4* __restrict__ msk,
    vfloat2* __restrict__ parts,
    unsigned int* __restrict__ tickets,   // [0..7] per-group, [8] global
    float* __restrict__ out)
{
    __shared__ float ssum[BLOCK / 64];
    __shared__ unsigned int scnt[BLOCK / 64];
    __shared__ int amLast;
    __shared__ float f1[BLOCK / 64];
    __shared__ float f2[BLOCK / 64];

    const long base = (long)blockIdx.x * (BLOCK * UNROLL) + threadIdx.x;

    vfloat4 a[UNROLL];
    vfloat4 b[UNROLL];
    vint4 m[UNROLL];
#pragma unroll
    for (int u = 0; u < UNROLL; ++u) {
        const long i = base + (long)u * BLOCK;   // wave-coalesced per u
        a[u] = __builtin_nontemporal_load(&inp[i]);
        b[u] = __builtin_nontemporal_load(&tgt[i]);
        m[u] = __builtin_nontemporal_load(&msk[i]);
    }

    float s = 0.0f;
    unsigned int c = 0u;
#pragma unroll
    for (int u = 0; u < UNROLL; ++u) {
        float d0 = a[u].x - b[u].x;
        float d1 = a[u].y - b[u].y;
        float d2 = a[u].z - b[u].z;
        float d3 = a[u].w - b[u].w;
        s += (float)m[u].x * d0 * d0;
        s += (float)m[u].y * d1 * d1;
        s += (float)m[u].z * d2 * d2;
        s += (float)m[u].w * d3 * d3;
        c += (unsigned int)(m[u].x + m[u].y + m[u].z + m[u].w);
    }

    // wave-64 shuffle reduction
#pragma unroll
    for (int off = 32; off > 0; off >>= 1) {
        s += __shfl_down(s, off, 64);
        c += __shfl_down(c, off, 64);
    }

    const int lane = threadIdx.x & 63;
    const int wave = threadIdx.x >> 6;
    if (lane == 0) {
        ssum[wave] = s;
        scnt[wave] = c;
    }
    __syncthreads();

    if (threadIdx.x == 0) {
        float bs = 0.0f;
        unsigned int bc = 0u;
#pragma unroll
        for (int w = 0; w < BLOCK / 64; ++w) {
            bs += ssum[w];
            bc += scnt[w];
        }
        // contention-free: each block owns its slot
        store_part_agent(&parts[blockIdx.x], bs, (float)bc);

        if (FINISH) {
            // Hierarchical ticket: 8 group lines then 1 global line.
            // ACQ_REL RMW chain -> finisher happens-after every partial store.
            const unsigned int g = blockIdx.x & 7u;
            const unsigned int nb = gridDim.x;
            const unsigned int gsz = nb / 8u + (g < (nb & 7u) ? 1u : 0u);
            int last = 0;
            unsigned int old = __hip_atomic_fetch_add(
                &tickets[g], 1u, __ATOMIC_ACQ_REL, __HIP_MEMORY_SCOPE_AGENT);
            if (old == gsz - 1u) {
                const unsigned int ng = nb < 8u ? nb : 8u;
                unsigned int o2 = __hip_atomic_fetch_add(
                    &tickets[8], 1u, __ATOMIC_ACQ_REL, __HIP_MEMORY_SCOPE_AGENT);
                last = (o2 == ng - 1u) ? 1 : 0;
            }
            amLast = last;
        } else {
            amLast = 0;
        }
    }

    if (FINISH) {
        __syncthreads();                 // block-uniform: amLast visible
        if (amLast) {
            // Unique winner block: reduce all partials (coalesced float2).
            float fs = 0.0f;
            float fc = 0.0f;
            for (unsigned int i = threadIdx.x; i < gridDim.x; i += BLOCK) {
                vfloat2 p = load_part_agent(&parts[i]);
                fs += p.x;
                fc += p.y;
            }
#pragma unroll
            for (int off = 32; off > 0; off >>= 1) {
                fs += __shfl_down(fs, off, 64);
                fc += __shfl_down(fc, off, 64);
            }
            if (lane == 0) { f1[wave] = fs; f2[wave] = fc; }
            __syncthreads();
            if (threadIdx.x == 0) {
                float ts = 0.0f, tc = 0.0f;
#pragma unroll
                for (int w = 0; w < BLOCK / 64; ++w) { ts += f1[w]; tc += f2[w]; }
                out[0] = ts / tc;
            }
        }
    }
}

// Tail for non-divisible sizes (not hit by the reference shape).
__global__ void masked_mse_tail(
    const float* __restrict__ inp,
    const float* __restrict__ tgt,
    const int* __restrict__ msk,
    vfloat2* __restrict__ parts,
    long start, long n, int tail_base)
{
    long i = start + blockIdx.x * (long)blockDim.x + threadIdx.x;
    float s = 0.0f;
    unsigned int c = 0u;
    for (; i < n; i += (long)gridDim.x * blockDim.x) {
        float d = inp[i] - tgt[i];
        int mv = msk[i];
        s += (float)mv * d * d;
        c += (unsigned int)mv;
    }
#pragma unroll
    for (int off = 32; off > 0; off >>= 1) {
        s += __shfl_down(s, off, 64);
        c += __shfl_down(c, off, 64);
    }
    __shared__ float ssum[4];
    __shared__ unsigned int scnt[4];
    const int lane = threadIdx.x & 63;
    const int wave = threadIdx.x >> 6;
    if (lane == 0) { ssum[wave] = s; scnt[wave] = c; }
    __syncthreads();
    if (threadIdx.x == 0) {
        float bs = 0.0f;
        unsigned int bc = 0u;
        for (int w = 0; w < (int)(blockDim.x / 64); ++w) { bs += ssum[w]; bc += scnt[w]; }
        vfloat2 p; p.x = bs; p.y = (float)bc;
        parts[tail_base + blockIdx.x] = p;
    }
}

// Fallback finisher (only when the tail kernel ran).
__global__ __launch_bounds__(256) void masked_mse_stage2(
    const vfloat2* __restrict__ parts,
    int nparts,
    float* __restrict__ out)
{
    float s = 0.0f;
    float c = 0.0f;
    for (int i = threadIdx.x; i < nparts; i += blockDim.x) {
        vfloat2 p = parts[i];
        s += p.x;
        c += p.y;
    }
#pragma unroll
    for (int off = 32; off > 0; off >>= 1) {
        s += __shfl_down(s, off, 64);
        c += __shfl_down(c, off, 64);
    }
    __shared__ float ssum[4];
    __shared__ float scnt[4];
    const int lane = threadIdx.x & 63;
    const int wave = threadIdx.x >> 6;
    if (lane == 0) { ssum[wave] = s; scnt[wave] = c; }
    __syncthreads();
    if (threadIdx.x == 0) {
        float ts = 0.0f, tc = 0.0f;
#pragma unroll
        for (int w = 0; w < 4; ++w) { ts += ssum[w]; tc += scnt[w]; }
        out[0] = ts / tc;
    }
}

extern "C" void kernel_launch(void* const* d_in, const int* in_sizes, int n_in,
                              void* d_out, int out_size, void* d_ws, size_t ws_size,
                              hipStream_t stream)
{
    const float* inp = (const float*)d_in[0];
    const float* tgt = (const float*)d_in[1];
    const int* msk = (const int*)d_in[2];
    const long n = in_sizes[0];
    const long n4 = n / 4;

    vfloat2* parts = (vfloat2*)d_ws;
    unsigned int* tickets =
        (unsigned int*)((char*)d_ws + (size_t)MAX_PARTS * sizeof(vfloat2));

    const long per_block = (long)BLOCK * UNROLL;     // float4s per block
    long nblocks = n4 / per_block;                   // 3072 for reference shape
    if (nblocks > MAX_PARTS - 64) nblocks = MAX_PARTS - 64;  // clamp (generality)
    const long covered = nblocks * per_block * 4;    // elements covered

    if (nblocks > 0 && covered == n) {
        // Fast path (reference shape): memset node + single fused kernel.
        hipMemsetAsync(tickets, 0, 64, stream);
        masked_mse_fused<1><<<(int)nblocks, BLOCK, 0, stream>>>(
            (const vfloat4*)inp, (const vfloat4*)tgt, (const vint4*)msk,
            parts, tickets, (float*)d_out);
        return;
    }

    // Generic fallback: partial-only main kernel + tail + finisher.
    int nparts = 0;
    if (nblocks > 0) {
        masked_mse_fused<0><<<(int)nblocks, BLOCK, 0, stream>>>(
            (const vfloat4*)inp, (const vfloat4*)tgt, (const vint4*)msk,
            parts, tickets, (float*)d_out);
        nparts = (int)nblocks;
    }
    if (covered < n) {
        masked_mse_tail<<<64, BLOCK, 0, stream>>>(
            inp, tgt, msk, parts, covered, n, nparts);
        nparts += 64;
    }
    masked_mse_stage2<<<1, 256, 0, stream>>>(parts, nparts, (float*)d_out);
}

// Round 2
// 247.620 us; speedup vs baseline: 1.6285x; 1.6285x over previous
//
#include <hip/hip_runtime.h>

// Masked MSE: out = sum((in-tgt)^2 * (mask==1)) / sum(mask==1)
// Memory-bound 3-stream read reduction (302 MB, no reuse).
// Floor: 302 MB / 6.29 TB/s (measured read ceiling) = 48.0 us.
//
// R5 insight: same-line atomics serialize at ~13-15 ns each.
// R6 (this structure): two-stage reduction, zero same-address atomics.
//   Stage 1 stores each block's partial to its own slot; stage 2 (1 block)
//   reduces 3072 partials. Measured 245.6 us headline.
// R7 FAILED (reverted): fusing stage2 via agent-scope ACQ_REL ticket chain
//   collapsed read BW 7x (207 us @ 738 GB/s). Agent scope spans the 8
//   non-coherent XCD L2s -> every acquire/release RMW emits L2
//   writeback/invalidate ops; 3072 block-leader flushes trashed the
//   streaming reads chip-wide. The ~5 us stage2 dispatch is two orders of
//   magnitude cheaper than the coherence traffic needed to replace it.
//   DO NOT re-attempt single-kernel cross-XCD reduction here.

#define BLOCK 256
#define UNROLL 8
#define MAX_PARTS 8192          // capacity for partials in d_ws (64 KB used)

typedef float vfloat4 __attribute__((ext_vector_type(4)));
typedef int   vint4   __attribute__((ext_vector_type(4)));

__global__ __launch_bounds__(BLOCK, 2) void masked_mse_stage1(
    const vfloat4* __restrict__ inp,
    const vfloat4* __restrict__ tgt,
    const vint4* __restrict__ msk,
    float* __restrict__ part_sum,
    unsigned int* __restrict__ part_cnt)
{
    const long base = (long)blockIdx.x * (BLOCK * UNROLL) + threadIdx.x;

    vfloat4 a[UNROLL];
    vfloat4 b[UNROLL];
    vint4 m[UNROLL];
#pragma unroll
    for (int u = 0; u < UNROLL; ++u) {
        const long i = base + (long)u * BLOCK;   // wave-coalesced per u
        a[u] = __builtin_nontemporal_load(&inp[i]);
        b[u] = __builtin_nontemporal_load(&tgt[i]);
        m[u] = __builtin_nontemporal_load(&msk[i]);
    }

    float s = 0.0f;
    unsigned int c = 0u;
#pragma unroll
    for (int u = 0; u < UNROLL; ++u) {
        float d0 = a[u].x - b[u].x;
        float d1 = a[u].y - b[u].y;
        float d2 = a[u].z - b[u].z;
        float d3 = a[u].w - b[u].w;
        s += (float)m[u].x * d0 * d0;
        s += (float)m[u].y * d1 * d1;
        s += (float)m[u].z * d2 * d2;
        s += (float)m[u].w * d3 * d3;
        c += (unsigned int)(m[u].x + m[u].y + m[u].z + m[u].w);
    }

    // wave-64 shuffle reduction
#pragma unroll
    for (int off = 32; off > 0; off >>= 1) {
        s += __shfl_down(s, off, 64);
        c += __shfl_down(c, off, 64);
    }

    __shared__ float ssum[BLOCK / 64];
    __shared__ unsigned int scnt[BLOCK / 64];
    const int lane = threadIdx.x & 63;
    const int wave = threadIdx.x >> 6;
    if (lane == 0) {
        ssum[wave] = s;
        scnt[wave] = c;
    }
    __syncthreads();
    if (threadIdx.x == 0) {
        float bs = 0.0f;
        unsigned int bc = 0u;
#pragma unroll
        for (int w = 0; w < BLOCK / 64; ++w) {
            bs += ssum[w];
            bc += scnt[w];
        }
        // contention-free: each block owns its slot
        part_sum[blockIdx.x] = bs;
        part_cnt[blockIdx.x] = bc;
    }
}

// Tail for non-divisible sizes (none for the reference shape).
// Writes partials to slots [tail_base, tail_base+gridDim.x).
__global__ void masked_mse_tail(
    const float* __restrict__ inp,
    const float* __restrict__ tgt,
    const int* __restrict__ msk,
    float* __restrict__ part_sum,
    unsigned int* __restrict__ part_cnt,
    long start, long n, int tail_base)
{
    long i = start + blockIdx.x * (long)blockDim.x + threadIdx.x;
    float s = 0.0f;
    unsigned int c = 0u;
    for (; i < n; i += (long)gridDim.x * blockDim.x) {
        float d = inp[i] - tgt[i];
        int mv = msk[i];
        s += (float)mv * d * d;
        c += (unsigned int)mv;
    }
#pragma unroll
    for (int off = 32; off > 0; off >>= 1) {
        s += __shfl_down(s, off, 64);
        c += __shfl_down(c, off, 64);
    }
    __shared__ float ssum[4];
    __shared__ unsigned int scnt[4];
    const int lane = threadIdx.x & 63;
    const int wave = threadIdx.x >> 6;
    if (lane == 0) { ssum[wave] = s; scnt[wave] = c; }
    __syncthreads();
    if (threadIdx.x == 0) {
        float bs = 0.0f;
        unsigned int bc = 0u;
        for (int w = 0; w < (int)(blockDim.x / 64); ++w) { bs += ssum[w]; bc += scnt[w]; }
        part_sum[tail_base + blockIdx.x] = bs;
        part_cnt[tail_base + blockIdx.x] = bc;
    }
}

__global__ __launch_bounds__(1024) void masked_mse_stage2(
    const float* __restrict__ part_sum,
    const unsigned int* __restrict__ part_cnt,
    int nparts,
    float* __restrict__ out)
{
    float s = 0.0f;
    unsigned int c = 0u;
    for (int i = threadIdx.x; i < nparts; i += blockDim.x) {
        s += part_sum[i];
        c += part_cnt[i];
    }
#pragma unroll
    for (int off = 32; off > 0; off >>= 1) {
        s += __shfl_down(s, off, 64);
        c += __shfl_down(c, off, 64);
    }
    __shared__ float ssum[16];
    __shared__ unsigned int scnt[16];
    const int lane = threadIdx.x & 63;
    const int wave = threadIdx.x >> 6;
    if (lane == 0) { ssum[wave] = s; scnt[wave] = c; }
    __syncthreads();
    if (threadIdx.x == 0) {
        float ts = 0.0f;
        unsigned int tc = 0u;
#pragma unroll
        for (int w = 0; w < 16; ++w) { ts += ssum[w]; tc += scnt[w]; }
        out[0] = ts / (float)tc;
    }
}

extern "C" void kernel_launch(void* const* d_in, const int* in_sizes, int n_in,
                              void* d_out, int out_size, void* d_ws, size_t ws_size,
                              hipStream_t stream)
{
    const float* inp = (const float*)d_in[0];
    const float* tgt = (const float*)d_in[1];
    const int* msk = (const int*)d_in[2];
    const long n = in_sizes[0];
    const long n4 = n / 4;

    float* part_sum = (float*)d_ws;
    unsigned int* part_cnt = (unsigned int*)((char*)d_ws + MAX_PARTS * sizeof(float));

    const long per_block = (long)BLOCK * UNROLL;     // float4s per block
    long nblocks = n4 / per_block;                   // 3072 for reference shape
    if (nblocks > MAX_PARTS - 64) nblocks = MAX_PARTS - 64;  // clamp (generality)

    int nparts = 0;
    if (nblocks > 0) {
        masked_mse_stage1<<<(int)nblocks, BLOCK, 0, stream>>>(
            (const vfloat4*)inp, (const vfloat4*)tgt, (const vint4*)msk,
            part_sum, part_cnt);
        nparts = (int)nblocks;
    }
    const long covered = nblocks * per_block * 4;    // elements covered
    if (covered < n) {
        masked_mse_tail<<<64, BLOCK, 0, stream>>>(
            inp, tgt, msk, part_sum, part_cnt, covered, n, nparts);
        nparts += 64;
    }
    masked_mse_stage2<<<1, 1024, 0, stream>>>(part_sum, part_cnt, nparts, (float*)d_out);
}